// Round 14
// baseline (696.828 us; speedup 1.0000x reference)
//
#include <hip/hip_runtime.h>
#include <hip/hip_bf16.h>
#include <hip/hip_fp16.h>
#include <stdint.h>

#define N_NODES 20000
#define HID 64
#define EPS 1e-5f

typedef _Float16 h2 __attribute__((ext_vector_type(2)));

__device__ __forceinline__ h2 u2h(uint32_t u) { union { uint32_t u; h2 h; } v; v.u = u; return v.h; }

// Per-graph pointer set. xl/xr stored fp16 [N,64] (2.5 MB each); with the
// attention parity split each XCD's hot gather set stays L2-resident.
struct GP {
    const int* ei;      // [2, E]
    const int* batch;   // [N] sorted
    const float* x;     // [N, 5]
    int* deg;           // rowptr after scan, N+1
    int* cursor;
    int* csr;           // E + N entries; values are BYTE offsets (src*128)
    float* h;           // [N, 64]
    __half* xlh;        // [N, 64] fp16
    __half* xrh;        // [N, 64] fp16
    float* gb;          // attention output (pre-BN)
    float* stats;       // 8 layers * 128 (sum, sumsq)
    float* osum;        // 32 * 64 pooled sums
};

// ---------------- CSR build (both graphs in one dispatch) ----------------

__global__ void k_csr_init(GP a, GP b, int n, int two) {
    int t = blockIdx.x * blockDim.x + threadIdx.x;
    if (t < n) {
        a.deg[t] = 1;  // self-loop
        if (two) b.deg[t] = 1;
    }
}

__global__ void k_count(GP a, GP b, int Ea, int Eb, int two) {
    int t = blockIdx.x * blockDim.x + threadIdx.x;
    if (t < Ea) atomicAdd(&a.deg[a.ei[Ea + t]], 1);
    if (two && t < Eb) atomicAdd(&b.deg[b.ei[Eb + t]], 1);
}

#define SCAN_T 1024
#define SCAN_C 20
__global__ __launch_bounds__(1024) void k_scan(GP a, GP b, int n, int totA, int totB) {
    GP g = blockIdx.x ? b : a;
    int total = blockIdx.x ? totB : totA;
    __shared__ int sd[SCAN_T];
    int t = threadIdx.x;
    int base = t * SCAN_C;
    int loc[SCAN_C];
    int s = 0;
#pragma unroll
    for (int i = 0; i < SCAN_C; ++i) {
        int idx = base + i;
        loc[i] = (idx < n) ? g.deg[idx] : 0;
        s += loc[i];
    }
    sd[t] = s;
    __syncthreads();
    for (int off = 1; off < SCAN_T; off <<= 1) {
        int v = (t >= off) ? sd[t - off] : 0;
        __syncthreads();
        sd[t] += v;
        __syncthreads();
    }
    int run = sd[t] - s;  // exclusive prefix
#pragma unroll
    for (int i = 0; i < SCAN_C; ++i) {
        int idx = base + i;
        if (idx < n) { g.deg[idx] = run; g.cursor[idx] = run; run += loc[i]; }
    }
    if (t == 0) g.deg[n] = total;
}

// csr values are byte offsets into 128 B fp16 rows: src * 128
__global__ void k_scatter(GP a, GP b, int Ea, int Eb, int n, int two) {
    int t = blockIdx.x * blockDim.x + threadIdx.x;
    if (t < Ea) {
        int s = a.ei[t], d = a.ei[Ea + t];
        a.csr[atomicAdd(&a.cursor[d], 1)] = s * 128;
    } else if (t < Ea + n) {
        int nn = t - Ea;
        a.csr[atomicAdd(&a.cursor[nn], 1)] = nn * 128;
    }
    if (two) {
        if (t < Eb) {
            int s = b.ei[t], d = b.ei[Eb + t];
            b.csr[atomicAdd(&b.cursor[d], 1)] = s * 128;
        } else if (t < Eb + n) {
            int nn = t - Eb;
            b.csr[atomicAdd(&b.cursor[nn], 1)] = nn * 128;
        }
    }
}

// ---------------- weight pre-pack: fp32 [8][64][64] -> h2-packed [8][32][64] --

__global__ void k_wcvt(const float* __restrict__ Wl, const float* __restrict__ Wr,
                       uint32_t* __restrict__ wpk) {
    int t = blockIdx.x * 256 + threadIdx.x;
    if (t >= 16384) return;
    int l = t >> 11, r = t & 2047;
    int k2 = r >> 6, c = r & 63;
    const float* wl = Wl + l * 4096;
    const float* wr = Wr + l * 4096;
    h2 a, b;
    a.x = (_Float16)wl[(2 * k2) * 64 + c];
    a.y = (_Float16)wl[(2 * k2 + 1) * 64 + c];
    b.x = (_Float16)wr[(2 * k2) * 64 + c];
    b.y = (_Float16)wr[(2 * k2 + 1) * 64 + c];
    union { h2 h; uint32_t u; } ua, ub;
    ua.h = a; ub.h = b;
    wpk[l * 4096 + r] = ua.u;
    wpk[l * 4096 + 2048 + r] = ub.u;
}

// ---------------- dual linear via v_dot2_f32_f16, fused with BN+ELU+res ------
// R12-proven shape: one exact 32-node tile per block (625 blocks/graph).
// Layer 0 computes h = x @ Wn + bnode inline (nodelin fused; x reads are
// wave-uniform broadcast loads).

__global__ __launch_bounds__(256) void k_lin2(GP ga, GP gbp, int nPer, int n,
        const uint32_t* __restrict__ wl2g, const float* __restrict__ bl,
        const uint32_t* __restrict__ wr2g, const float* __restrict__ br,
        const float* __restrict__ gamma, const float* __restrict__ beta,
        const float* __restrict__ Wn, const float* __restrict__ bn, int layer) {
    __shared__ uint32_t wl2[2048], wr2[2048];  // h2-packed [k2][c]
    __shared__ _Float16 hs16[2048];            // [wave][node j][k]
    int bid = blockIdx.x;
    GP g = ga;
    if (bid >= nPer) { g = gbp; bid -= nPer; }
    {
        uint4* dl = (uint4*)wl2; const uint4* sl = (const uint4*)wl2g;
        uint4* dr = (uint4*)wr2; const uint4* sr = (const uint4*)wr2g;
        for (int i = threadIdx.x; i < 512; i += 256) { dl[i] = sl[i]; dr[i] = sr[i]; }
    }
    int c = threadIdx.x & 63;
    int wid = threadIdx.x >> 6;
    float blv = bl[c], brv = br[c];
    float mu = 0.f, inv = 1.f, gam = 1.f, bet = 0.f;
    float wn_c[5], bnv = 0.f;
    if (layer > 0) {
        const float* st = g.stats + (layer - 1) * 128;
        float invn = 1.0f / (float)n;
        mu = st[c] * invn;
        float var = st[64 + c] * invn - mu * mu;
        inv = rsqrtf(fmaxf(var, 0.f) + EPS);
        gam = gamma[c]; bet = beta[c];
    } else {
#pragma unroll
        for (int k = 0; k < 5; ++k) wn_c[k] = Wn[k * HID + c];
        bnv = bn[c];
    }
    int nb = bid * 32 + wid * 8;  // 625*32 == 20000: always a full tile
    size_t off0 = (size_t)nb * 64 + c;
    float hv[8];
    if (layer > 0) {
#pragma unroll
        for (int j = 0; j < 8; ++j) {
            float gv = g.gb[off0 + j * 64];
            float ov = g.h[off0 + j * 64];
            float v = (gv - mu) * inv * gam + bet;
            v = v > 0.f ? v : expm1f(v);
            hv[j] = ov + v;
            g.h[off0 + j * 64] = hv[j];
        }
    } else {
        // fused node linear: h = x @ Wn + bnode
#pragma unroll
        for (int j = 0; j < 8; ++j) {
            const float* xr = g.x + (size_t)(nb + j) * 5;
            float acc = bnv;
#pragma unroll
            for (int k = 0; k < 5; ++k) acc = fmaf(xr[k], wn_c[k], acc);
            hv[j] = acc;
            g.h[off0 + j * 64] = acc;
        }
    }
    _Float16* hw16 = &hs16[wid * 512];
#pragma unroll
    for (int j = 0; j < 8; ++j) hw16[j * 64 + c] = (_Float16)hv[j];
    __syncthreads();  // weights + (wave-private) h tile staged
    const uint32_t* hw2 = (const uint32_t*)hw16;
    float accl[8], accr[8];
#pragma unroll
    for (int j = 0; j < 8; ++j) { accl[j] = blv; accr[j] = brv; }
    for (int k8 = 0; k8 < 8; ++k8) {
        uint4 hq[8];
#pragma unroll
        for (int j = 0; j < 8; ++j) hq[j] = *(const uint4*)&hw2[j * 32 + k8 * 4];
#pragma unroll
        for (int p = 0; p < 4; ++p) {
            h2 wlv = u2h(wl2[(k8 * 4 + p) * 64 + c]);
            h2 wrv = u2h(wr2[(k8 * 4 + p) * 64 + c]);
#pragma unroll
            for (int j = 0; j < 8; ++j) {
                h2 hp = u2h((&hq[j].x)[p]);
                accl[j] = __builtin_amdgcn_fdot2(hp, wlv, accl[j], false);
                accr[j] = __builtin_amdgcn_fdot2(hp, wrv, accr[j], false);
            }
        }
    }
#pragma unroll
    for (int j = 0; j < 8; ++j) {
        g.xlh[off0 + j * 64] = __float2half(accl[j]);
        g.xrh[off0 + j * 64] = __float2half(accr[j]);
    }
}

// ---------------- attention: packed fp16, 2 edges/wave (R10-proven) -----------
// Score dot via fdot2 (fp16 att coeffs, fp32 accumulate).

__device__ __forceinline__ float red8(float p) {
    p += __int_as_float(__builtin_amdgcn_update_dpp(0, __float_as_int(p), 0xB1, 0xF, 0xF, true));  // quad xor1
    p += __int_as_float(__builtin_amdgcn_update_dpp(0, __float_as_int(p), 0x4E, 0xF, 0xF, true));  // quad xor2
    p += __int_as_float(__builtin_amdgcn_update_dpp(0, __float_as_int(p), 0x141, 0xF, 0xF, true)); // half-mirror (8)
    return p;
}

__global__ __launch_bounds__(1024) void k_attn(GP ga, GP gbp, int nPer,
        const float* __restrict__ att, const float* __restrict__ cbias, int layer, int n) {
    int bid = blockIdx.x;
    GP g = (bid & 1) ? gbp : ga;   // parity -> XCD partitioning
    bid >>= 1;
    int lane = threadIdx.x & 63;
    int wid = threadIdx.x >> 6;
    int hh = lane >> 5;            // edge slot (0=A, 1=B)
    int cl = lane & 31;            // half2 slot: channels 2cl, 2cl+1
    int gw = bid * 16 + wid;
    int nw = nPer * 16;
    const float LOG2E = 1.44269504f;
    h2 ap;
    ap.x = (_Float16)(att[2 * cl] * LOG2E);
    ap.y = (_Float16)(att[2 * cl + 1] * LOG2E);
    float cb0 = cbias[2 * cl], cb1 = cbias[2 * cl + 1];
    const h2 slope = {(_Float16)0.2f, (_Float16)0.2f};
    const int* __restrict__ rowptr = g.deg;
    const int* __restrict__ csr = g.csr;
    const char* xlb = (const char*)g.xlh + (size_t)cl * 4;  // lane-fixed base
    const char* xrb = (const char*)g.xrh + (size_t)cl * 4;
    float* __restrict__ gbuf = g.gb;
    float* st = g.stats + layer * 128;
    float bs0 = 0.f, bs1 = 0.f, bq0 = 0.f, bq1 = 0.f;
    for (int node = gw; node < n; node += nw) {
        int start = rowptr[node], end = rowptr[node + 1];
        h2 xrv = *(const h2*)(xrb + (size_t)node * 128);
        // self score as softmax stabilizer (exact: shift invariance)
        float sself;
        {
            h2 xs = *(const h2*)(xlb + (size_t)node * 128);
            h2 t = xs + xrv;
            h2 lk = __builtin_elementwise_max(t, t * slope);
            float sp = __builtin_amdgcn_fdot2(lk, ap, 0.f, false);
            sself = red8(sp);
        }
        float lsum = 0.f, acc0 = 0.f, acc1 = 0.f;
        int idx = start;
        for (; idx + 16 <= end; idx += 16) {  // 8 pairs, 16 loads in flight
            int off[8];
            h2 xv[8];
#pragma unroll
            for (int j = 0; j < 8; ++j) off[j] = csr[idx + 2 * j + hh];
#pragma unroll
            for (int j = 0; j < 8; ++j) xv[j] = *(const h2*)(xlb + off[j]);
#pragma unroll
            for (int j = 0; j < 8; ++j) {
                h2 t = xv[j] + xrv;
                h2 lk = __builtin_elementwise_max(t, t * slope);
                float sp = __builtin_amdgcn_fdot2(lk, ap, 0.f, false);
                float w = exp2f(fminf(red8(sp) - sself, 110.f));
                lsum += w;
                acc0 = fmaf(w, (float)xv[j].x, acc0);
                acc1 = fmaf(w, (float)xv[j].y, acc1);
            }
        }
        for (; idx + 8 <= end; idx += 8) {   // 4 pairs
            int off[4];
            h2 xv[4];
#pragma unroll
            for (int j = 0; j < 4; ++j) off[j] = csr[idx + 2 * j + hh];
#pragma unroll
            for (int j = 0; j < 4; ++j) xv[j] = *(const h2*)(xlb + off[j]);
#pragma unroll
            for (int j = 0; j < 4; ++j) {
                h2 t = xv[j] + xrv;
                h2 lk = __builtin_elementwise_max(t, t * slope);
                float sp = __builtin_amdgcn_fdot2(lk, ap, 0.f, false);
                float w = exp2f(fminf(red8(sp) - sself, 110.f));
                lsum += w;
                acc0 = fmaf(w, (float)xv[j].x, acc0);
                acc1 = fmaf(w, (float)xv[j].y, acc1);
            }
        }
        for (; idx < end; idx += 2) {         // masked pairs
            int e = idx + hh;
            bool valid = e < end;
            int off = csr[valid ? e : end - 1];
            h2 xv = *(const h2*)(xlb + off);
            h2 t = xv + xrv;
            h2 lk = __builtin_elementwise_max(t, t * slope);
            float sp = __builtin_amdgcn_fdot2(lk, ap, 0.f, false);
            float w = exp2f(fminf(red8(sp) - sself, 110.f));
            w = valid ? w : 0.f;
            lsum += w;
            acc0 = fmaf(w, (float)xv.x, acc0);
            acc1 = fmaf(w, (float)xv.y, acc1);
        }
        // combine edge slots A/B (same channels, disjoint edges)
        lsum += __shfl_xor(lsum, 32);
        acc0 += __shfl_xor(acc0, 32);
        acc1 += __shfl_xor(acc1, 32);
        if (hh == 0) {
            float invl = 1.0f / lsum;
            float o0 = acc0 * invl + cb0;
            float o1 = acc1 * invl + cb1;
            float2 o = {o0, o1};
            *(float2*)(gbuf + (size_t)node * 64 + 2 * cl) = o;
            bs0 += o0; bs1 += o1;
            bq0 += o0 * o0; bq1 += o1 * o1;
        }
    }
    // block-reduce BN stats (channels 2cl, 2cl+1 live in lanes 0-31 of each wave)
    __shared__ float2 sred[1024];
    float2 z = {0.f, 0.f};
    float2 v1 = {bs0, bs1};
    sred[threadIdx.x] = (hh == 0) ? v1 : z;
    __syncthreads();
    if (threadIdx.x < 32) {
        float t0 = 0.f, t1 = 0.f;
#pragma unroll
        for (int w = 0; w < 16; ++w) { float2 s = sred[w * 64 + threadIdx.x]; t0 += s.x; t1 += s.y; }
        atomicAdd(&st[2 * threadIdx.x], t0);
        atomicAdd(&st[2 * threadIdx.x + 1], t1);
    }
    __syncthreads();
    float2 v2 = {bq0, bq1};
    sred[threadIdx.x] = (hh == 0) ? v2 : z;
    __syncthreads();
    if (threadIdx.x < 32) {
        float t0 = 0.f, t1 = 0.f;
#pragma unroll
        for (int w = 0; w < 16; ++w) { float2 s = sred[w * 64 + threadIdx.x]; t0 += s.x; t1 += s.y; }
        atomicAdd(&st[64 + 2 * threadIdx.x], t0);
        atomicAdd(&st[64 + 2 * threadIdx.x + 1], t1);
    }
}

// ---------------- pool, fused with layer-7 BN+ELU+residual ----------------

__global__ __launch_bounds__(256) void k_pool(GP ga, GP gbp, int nPer,
        const float* __restrict__ gamma, const float* __restrict__ beta, int n) {
    int bid = blockIdx.x;
    GP g = ga;
    if (bid >= nPer) { g = gbp; bid -= nPer; }
    int lane = threadIdx.x & 63, w = threadIdx.x >> 6;
    const float* st = g.stats + 7 * 128;
    float invn = 1.f / (float)n;
    float mu = st[lane] * invn;
    float var = st[64 + lane] * invn - mu * mu;
    float inv = rsqrtf(fmaxf(var, 0.f) + EPS);
    float gam = gamma[lane], bet = beta[lane];
    int chunk = (n + nPer - 1) / nPer;
    int s = bid * chunk;
    int e = min(s + chunk, n);
    float acc = 0.f;
    int cur = -1;
    for (int node = s + w; node < e; node += 4) {
        int bg = g.batch[node];  // wave-uniform
        size_t off = (size_t)node * 64 + lane;
        float gv = g.gb[off];
        float hv = g.h[off];
        float v = (gv - mu) * inv * gam + bet;
        float hn = hv + (v > 0.f ? v : expm1f(v));
        if (bg != cur) {
            if (cur >= 0) atomicAdd(&g.osum[cur * 64 + lane], acc);
            acc = 0.f; cur = bg;
        }
        acc += hn;
    }
    if (cur >= 0) atomicAdd(&g.osum[cur * 64 + lane], acc);
}

// ---------------- FC head (divides pooled sums by counts) ----------------

__device__ __forceinline__ int lb(const int* __restrict__ b, int n, int v) {
    int lo = 0, hi = n;
    while (lo < hi) { int mid = (lo + hi) >> 1; if (b[mid] < v) lo = mid + 1; else hi = mid; }
    return lo;
}

__global__ __launch_bounds__(256) void k_fc(const float* __restrict__ o1, const float* __restrict__ o2,
                                            const int* __restrict__ b1, const int* __restrict__ b2,
                                            const float* __restrict__ f1w, const float* __restrict__ f1b,
                                            const float* __restrict__ f2w, const float* __restrict__ f2b,
                                            const float* __restrict__ f3w, const float* __restrict__ f3b,
                                            float* __restrict__ out, int n) {
    int gid = blockIdx.x, t = threadIdx.x;
    __shared__ float cin[128];
    __shared__ float h1[256];
    __shared__ float red[128];
    __shared__ int cnts[2];
    if (t == 0) cnts[0] = lb(b1, n, gid + 1) - lb(b1, n, gid);
    if (t == 1) cnts[1] = lb(b2, n, gid + 1) - lb(b2, n, gid);
    __syncthreads();
    if (t < 64) {
        float c1 = (float)(cnts[0] > 0 ? cnts[0] : 1);
        float c2 = (float)(cnts[1] > 0 ? cnts[1] : 1);
        cin[t] = o1[gid * 64 + t] / c1;
        cin[64 + t] = o2[gid * 64 + t] / c2;
    }
    __syncthreads();
    float a = f1b[t];
#pragma unroll 8
    for (int k = 0; k < 128; ++k) a += cin[k] * f1w[k * 256 + t];
    h1[t] = fmaxf(a, 0.f);
    __syncthreads();
    if (t < 128) {
        float a2 = f2b[t];
#pragma unroll 8
        for (int k = 0; k < 256; ++k) a2 += h1[k] * f2w[k * 128 + t];
        red[t] = fmaxf(a2, 0.f) * f3w[t];
    }
    __syncthreads();
    for (int off = 64; off > 0; off >>= 1) {
        if (t < off) red[t] += red[t + off];
        __syncthreads();
    }
    if (t == 0) out[gid] = red[0] + f3b[0];
}

// ---------------- host ----------------

extern "C" void kernel_launch(void* const* d_in, const int* in_sizes, int n_in,
                              void* d_out, int out_size, void* d_ws, size_t ws_size,
                              hipStream_t stream) {
    const float* x1 = (const float*)d_in[0];
    const float* x2 = (const float*)d_in[1];
    const int* ei1 = (const int*)d_in[2];
    const int* ei2 = (const int*)d_in[3];
    const int* b1 = (const int*)d_in[4];
    const int* b2 = (const int*)d_in[5];
    const float* Wn = (const float*)d_in[6];
    const float* bnode = (const float*)d_in[7];
    const float* Wl = (const float*)d_in[8];
    const float* bl = (const float*)d_in[9];
    const float* Wr = (const float*)d_in[10];
    const float* br = (const float*)d_in[11];
    const float* att = (const float*)d_in[12];
    const float* cbias = (const float*)d_in[13];
    const float* gamma = (const float*)d_in[14];
    const float* beta = (const float*)d_in[15];
    const float* f1w = (const float*)d_in[16];
    const float* f1b = (const float*)d_in[17];
    const float* f2w = (const float*)d_in[18];
    const float* f2b = (const float*)d_in[19];
    const float* f3w = (const float*)d_in[20];
    const float* f3b = (const float*)d_in[21];
    float* out = (float*)d_out;

    const int N = N_NODES;
    const int EA = in_sizes[2] / 2;
    const int EB = in_sizes[3] / 2;
    const size_t INT_PG = 20096 + 20096 + 340096;  // deg, cursor, csr
    const size_t BIG = (size_t)N * 64;             // float-sized slot
    const size_t SMALL = 2 * 1024 + 2 * 2048;      // stats + osum
    const size_t WPK = 32768;                      // packed fp16 weights (uint32)
    const size_t dualBytes = 2 * INT_PG * 4 + (8 * BIG + SMALL + WPK) * 4;
    const int dual = (ws_size >= dualBytes) ? 1 : 0;

    int* ibase = (int*)d_ws;
    int* iA = ibase;
    int* iB = dual ? ibase + INT_PG : ibase;
    float* fbase = (float*)(ibase + (size_t)(dual ? 2 : 1) * INT_PG);
    float* hA = fbase;
    float* xlA = hA + BIG;      // fp16 xl (half of slot)
    float* xrA = xlA + BIG;     // fp16 xr (half of slot)
    float* gbA = xrA + BIG;
    float* hB = dual ? gbA + BIG : hA;
    float* xlB = dual ? hB + BIG : xlA;
    float* xrB = dual ? xlB + BIG : xrA;
    float* gbB = dual ? xrB + BIG : gbA;
    float* small = dual ? gbB + BIG : gbA + BIG;
    float* statsA = small;
    float* statsB = small + 1024;
    float* osumA = small + 2048;
    float* osumB = small + 4096;
    uint32_t* wpk = (uint32_t*)(small + SMALL);

    GP A, B;
    A.ei = ei1; A.batch = b1; A.x = x1;
    A.deg = iA; A.cursor = iA + 20096; A.csr = iA + 40192;
    A.h = hA; A.xlh = (__half*)xlA; A.xrh = (__half*)xrA;
    A.gb = gbA; A.stats = statsA; A.osum = osumA;
    B.ei = ei2; B.batch = b2; B.x = x2;
    B.deg = iB; B.cursor = iB + 20096; B.csr = iB + 40192;
    B.h = hB; B.xlh = (__half*)xlB; B.xrh = (__half*)xrB;
    B.gb = gbB; B.stats = statsB; B.osum = osumB;

    hipMemsetAsync(small, 0, SMALL * sizeof(float), stream);

    const int LIN2_NB = 625;   // per graph: one exact 32-node tile per block
    const int ATT_NB = 256;    // per graph, 1024-thread blocks, parity split
    const int POOL_NB = 250;   // per graph

    if (dual) {
        int Emax = EA > EB ? EA : EB;
        k_csr_init<<<(N + 255) / 256, 256, 0, stream>>>(A, B, N, 1);
        k_count<<<(Emax + 255) / 256, 256, 0, stream>>>(A, B, EA, EB, 1);
        k_scan<<<2, 1024, 0, stream>>>(A, B, N, EA + N, EB + N);
        k_scatter<<<(Emax + N + 255) / 256, 256, 0, stream>>>(A, B, EA, EB, N, 1);
        k_wcvt<<<64, 256, 0, stream>>>(Wl, Wr, wpk);
        for (int l = 0; l < 8; ++l) {
            const float* gm = l ? gamma + (l - 1) * 64 : gamma;
            const float* bt = l ? beta + (l - 1) * 64 : beta;
            k_lin2<<<2 * LIN2_NB, 256, 0, stream>>>(A, B, LIN2_NB, N,
                                                    wpk + l * 4096, bl + l * 64,
                                                    wpk + l * 4096 + 2048, br + l * 64, gm, bt,
                                                    Wn, bnode, l);
            k_attn<<<2 * ATT_NB, 1024, 0, stream>>>(A, B, ATT_NB, att + l * 64, cbias + l * 64, l, N);
        }
        k_pool<<<2 * POOL_NB, 256, 0, stream>>>(A, B, POOL_NB, gamma + 7 * 64, beta + 7 * 64, N);
    } else {
        for (int gi = 0; gi < 2; ++gi) {
            GP G = gi ? B : A;
            int E = gi ? EB : EA;
            k_csr_init<<<(N + 255) / 256, 256, 0, stream>>>(G, G, N, 0);
            k_count<<<(E + 255) / 256, 256, 0, stream>>>(G, G, E, E, 0);
            k_scan<<<1, 1024, 0, stream>>>(G, G, N, E + N, E + N);
            k_scatter<<<(E + N + 255) / 256, 256, 0, stream>>>(G, G, E, E, N, 0);
            if (gi == 0) k_wcvt<<<64, 256, 0, stream>>>(Wl, Wr, wpk);
            for (int l = 0; l < 8; ++l) {
                const float* gm = l ? gamma + (l - 1) * 64 : gamma;
                const float* bt = l ? beta + (l - 1) * 64 : beta;
                k_lin2<<<LIN2_NB, 256, 0, stream>>>(G, G, LIN2_NB, N,
                                                    wpk + l * 4096, bl + l * 64,
                                                    wpk + l * 4096 + 2048, br + l * 64, gm, bt,
                                                    Wn, bnode, l);
                k_attn<<<2 * ATT_NB, 1024, 0, stream>>>(G, G, ATT_NB, att + l * 64, cbias + l * 64, l, N);
            }
            k_pool<<<POOL_NB, 256, 0, stream>>>(G, G, POOL_NB, gamma + 7 * 64, beta + 7 * 64, N);
        }
    }
    k_fc<<<32, 256, 0, stream>>>(osumA, osumB, b1, b2, f1w, f1b, f2w, f2b, f3w, f3b, out, N);
}

// Round 15
// 629.953 us; speedup vs baseline: 1.1062x; 1.1062x over previous
//
#include <hip/hip_runtime.h>
#include <hip/hip_bf16.h>
#include <hip/hip_fp16.h>
#include <stdint.h>

#define N_NODES 20000
#define HID 64
#define EPS 1e-5f

typedef _Float16 h2 __attribute__((ext_vector_type(2)));

__device__ __forceinline__ h2 u2h(uint32_t u) { union { uint32_t u; h2 h; } v; v.u = u; return v.h; }

// Per-graph pointer set. xl/xr stored fp16 [N,64] (2.5 MB each); with the
// attention parity split each XCD's hot gather set stays L2-resident.
struct GP {
    const int* ei;      // [2, E]
    const int* batch;   // [N] sorted
    const float* x;     // [N, 5]
    int* deg;           // rowptr after scan, N+1
    int* cursor;
    int* csr;           // E + N entries; values are BYTE offsets (src*128)
    float* h;           // [N, 64]
    __half* xlh;        // [N, 64] fp16
    __half* xrh;        // [N, 64] fp16
    float* gb;          // attention output (pre-BN)
    float* stats;       // 8 layers * 128 (sum, sumsq)
    float* osum;        // 32 * 64 pooled sums
};

// ---------------- CSR build (both graphs in one dispatch) ----------------

__global__ void k_csr_init(GP a, GP b, int n, int two) {
    int t = blockIdx.x * blockDim.x + threadIdx.x;
    if (t < n) {
        a.deg[t] = 1;  // self-loop
        if (two) b.deg[t] = 1;
    }
}

__global__ void k_count(GP a, GP b, int Ea, int Eb, int two) {
    int t = blockIdx.x * blockDim.x + threadIdx.x;
    if (t < Ea) atomicAdd(&a.deg[a.ei[Ea + t]], 1);
    if (two && t < Eb) atomicAdd(&b.deg[b.ei[Eb + t]], 1);
}

#define SCAN_T 1024
#define SCAN_C 20
__global__ __launch_bounds__(1024) void k_scan(GP a, GP b, int n, int totA, int totB) {
    GP g = blockIdx.x ? b : a;
    int total = blockIdx.x ? totB : totA;
    __shared__ int sd[SCAN_T];
    int t = threadIdx.x;
    int base = t * SCAN_C;
    int loc[SCAN_C];
    int s = 0;
#pragma unroll
    for (int i = 0; i < SCAN_C; ++i) {
        int idx = base + i;
        loc[i] = (idx < n) ? g.deg[idx] : 0;
        s += loc[i];
    }
    sd[t] = s;
    __syncthreads();
    for (int off = 1; off < SCAN_T; off <<= 1) {
        int v = (t >= off) ? sd[t - off] : 0;
        __syncthreads();
        sd[t] += v;
        __syncthreads();
    }
    int run = sd[t] - s;  // exclusive prefix
#pragma unroll
    for (int i = 0; i < SCAN_C; ++i) {
        int idx = base + i;
        if (idx < n) { g.deg[idx] = run; g.cursor[idx] = run; run += loc[i]; }
    }
    if (t == 0) g.deg[n] = total;
}

// csr values are byte offsets into 128 B fp16 rows: src * 128
__global__ void k_scatter(GP a, GP b, int Ea, int Eb, int n, int two) {
    int t = blockIdx.x * blockDim.x + threadIdx.x;
    if (t < Ea) {
        int s = a.ei[t], d = a.ei[Ea + t];
        a.csr[atomicAdd(&a.cursor[d], 1)] = s * 128;
    } else if (t < Ea + n) {
        int nn = t - Ea;
        a.csr[atomicAdd(&a.cursor[nn], 1)] = nn * 128;
    }
    if (two) {
        if (t < Eb) {
            int s = b.ei[t], d = b.ei[Eb + t];
            b.csr[atomicAdd(&b.cursor[d], 1)] = s * 128;
        } else if (t < Eb + n) {
            int nn = t - Eb;
            b.csr[atomicAdd(&b.cursor[nn], 1)] = nn * 128;
        }
    }
}

// ---------------- weight pre-pack: fp32 [8][64][64] -> h2-packed [8][32][64] --

__global__ void k_wcvt(const float* __restrict__ Wl, const float* __restrict__ Wr,
                       uint32_t* __restrict__ wpk) {
    int t = blockIdx.x * 256 + threadIdx.x;
    if (t >= 16384) return;
    int l = t >> 11, r = t & 2047;
    int k2 = r >> 6, c = r & 63;
    const float* wl = Wl + l * 4096;
    const float* wr = Wr + l * 4096;
    h2 a, b;
    a.x = (_Float16)wl[(2 * k2) * 64 + c];
    a.y = (_Float16)wl[(2 * k2 + 1) * 64 + c];
    b.x = (_Float16)wr[(2 * k2) * 64 + c];
    b.y = (_Float16)wr[(2 * k2 + 1) * 64 + c];
    union { h2 h; uint32_t u; } ua, ub;
    ua.h = a; ub.h = b;
    wpk[l * 4096 + r] = ua.u;
    wpk[l * 4096 + 2048 + r] = ub.u;
}

// ---------------- dual linear via v_dot2_f32_f16, fused with BN+ELU+res ------
// R12-proven shape: one exact 32-node tile per block (625 blocks/graph).
// Layer 0 computes h = x @ Wn + bnode inline (nodelin fused).

__global__ __launch_bounds__(256) void k_lin2(GP ga, GP gbp, int nPer, int n,
        const uint32_t* __restrict__ wl2g, const float* __restrict__ bl,
        const uint32_t* __restrict__ wr2g, const float* __restrict__ br,
        const float* __restrict__ gamma, const float* __restrict__ beta,
        const float* __restrict__ Wn, const float* __restrict__ bn, int layer) {
    __shared__ uint32_t wl2[2048], wr2[2048];  // h2-packed [k2][c]
    __shared__ _Float16 hs16[2048];            // [wave][node j][k]
    int bid = blockIdx.x;
    GP g = ga;
    if (bid >= nPer) { g = gbp; bid -= nPer; }
    {
        uint4* dl = (uint4*)wl2; const uint4* sl = (const uint4*)wl2g;
        uint4* dr = (uint4*)wr2; const uint4* sr = (const uint4*)wr2g;
        for (int i = threadIdx.x; i < 512; i += 256) { dl[i] = sl[i]; dr[i] = sr[i]; }
    }
    int c = threadIdx.x & 63;
    int wid = threadIdx.x >> 6;
    float blv = bl[c], brv = br[c];
    float mu = 0.f, inv = 1.f, gam = 1.f, bet = 0.f;
    float wn_c[5], bnv = 0.f;
    if (layer > 0) {
        const float* st = g.stats + (layer - 1) * 128;
        float invn = 1.0f / (float)n;
        mu = st[c] * invn;
        float var = st[64 + c] * invn - mu * mu;
        inv = rsqrtf(fmaxf(var, 0.f) + EPS);
        gam = gamma[c]; bet = beta[c];
    } else {
#pragma unroll
        for (int k = 0; k < 5; ++k) wn_c[k] = Wn[k * HID + c];
        bnv = bn[c];
    }
    int nb = bid * 32 + wid * 8;  // 625*32 == 20000: always a full tile
    size_t off0 = (size_t)nb * 64 + c;
    float hv[8];
    if (layer > 0) {
#pragma unroll
        for (int j = 0; j < 8; ++j) {
            float gv = g.gb[off0 + j * 64];
            float ov = g.h[off0 + j * 64];
            float v = (gv - mu) * inv * gam + bet;
            v = v > 0.f ? v : expm1f(v);
            hv[j] = ov + v;
            g.h[off0 + j * 64] = hv[j];
        }
    } else {
        // fused node linear: h = x @ Wn + bnode
#pragma unroll
        for (int j = 0; j < 8; ++j) {
            const float* xr = g.x + (size_t)(nb + j) * 5;
            float acc = bnv;
#pragma unroll
            for (int k = 0; k < 5; ++k) acc = fmaf(xr[k], wn_c[k], acc);
            hv[j] = acc;
            g.h[off0 + j * 64] = acc;
        }
    }
    _Float16* hw16 = &hs16[wid * 512];
#pragma unroll
    for (int j = 0; j < 8; ++j) hw16[j * 64 + c] = (_Float16)hv[j];
    __syncthreads();  // weights + (wave-private) h tile staged
    const uint32_t* hw2 = (const uint32_t*)hw16;
    float accl[8], accr[8];
#pragma unroll
    for (int j = 0; j < 8; ++j) { accl[j] = blv; accr[j] = brv; }
    for (int k8 = 0; k8 < 8; ++k8) {
        uint4 hq[8];
#pragma unroll
        for (int j = 0; j < 8; ++j) hq[j] = *(const uint4*)&hw2[j * 32 + k8 * 4];
#pragma unroll
        for (int p = 0; p < 4; ++p) {
            h2 wlv = u2h(wl2[(k8 * 4 + p) * 64 + c]);
            h2 wrv = u2h(wr2[(k8 * 4 + p) * 64 + c]);
#pragma unroll
            for (int j = 0; j < 8; ++j) {
                h2 hp = u2h((&hq[j].x)[p]);
                accl[j] = __builtin_amdgcn_fdot2(hp, wlv, accl[j], false);
                accr[j] = __builtin_amdgcn_fdot2(hp, wrv, accr[j], false);
            }
        }
    }
#pragma unroll
    for (int j = 0; j < 8; ++j) {
        g.xlh[off0 + j * 64] = __float2half(accl[j]);
        g.xrh[off0 + j * 64] = __float2half(accr[j]);
    }
}

// ---------------- attention: packed fp16, 2 edges/wave (R12-proven exactly) ---
// Score path: fp32 fma_mix pair (fdot2 here REGRESSED ~4us/dispatch - R13/R14).

__device__ __forceinline__ float red8(float p) {
    p += __int_as_float(__builtin_amdgcn_update_dpp(0, __float_as_int(p), 0xB1, 0xF, 0xF, true));  // quad xor1
    p += __int_as_float(__builtin_amdgcn_update_dpp(0, __float_as_int(p), 0x4E, 0xF, 0xF, true));  // quad xor2
    p += __int_as_float(__builtin_amdgcn_update_dpp(0, __float_as_int(p), 0x141, 0xF, 0xF, true)); // half-mirror (8)
    return p;
}

__global__ __launch_bounds__(1024) void k_attn(GP ga, GP gbp, int nPer,
        const float* __restrict__ att, const float* __restrict__ cbias, int layer, int n) {
    int bid = blockIdx.x;
    GP g = (bid & 1) ? gbp : ga;   // parity -> XCD partitioning
    bid >>= 1;
    int lane = threadIdx.x & 63;
    int wid = threadIdx.x >> 6;
    int hh = lane >> 5;            // edge slot (0=A, 1=B)
    int cl = lane & 31;            // half2 slot: channels 2cl, 2cl+1
    int gw = bid * 16 + wid;
    int nw = nPer * 16;
    const float LOG2E = 1.44269504f;
    float a0 = att[2 * cl] * LOG2E;
    float a1 = att[2 * cl + 1] * LOG2E;
    float cb0 = cbias[2 * cl], cb1 = cbias[2 * cl + 1];
    const h2 slope = {(_Float16)0.2f, (_Float16)0.2f};
    const int* __restrict__ rowptr = g.deg;
    const int* __restrict__ csr = g.csr;
    const char* xlb = (const char*)g.xlh + (size_t)cl * 4;  // lane-fixed base
    const char* xrb = (const char*)g.xrh + (size_t)cl * 4;
    float* __restrict__ gbuf = g.gb;
    float* st = g.stats + layer * 128;
    float bs0 = 0.f, bs1 = 0.f, bq0 = 0.f, bq1 = 0.f;
    for (int node = gw; node < n; node += nw) {
        int start = rowptr[node], end = rowptr[node + 1];
        h2 xrv = *(const h2*)(xrb + (size_t)node * 128);
        // self score as softmax stabilizer (exact: shift invariance)
        float sself;
        {
            h2 xs = *(const h2*)(xlb + (size_t)node * 128);
            h2 t = xs + xrv;
            h2 lk = __builtin_elementwise_max(t, t * slope);
            float sp = fmaf((float)lk.x, a0, (float)lk.y * a1);
            sself = red8(sp);
        }
        float lsum = 0.f, acc0 = 0.f, acc1 = 0.f;
        int idx = start;
        for (; idx + 16 <= end; idx += 16) {  // 8 pairs, 16 loads in flight
            int off[8];
            h2 xv[8];
#pragma unroll
            for (int j = 0; j < 8; ++j) off[j] = csr[idx + 2 * j + hh];
#pragma unroll
            for (int j = 0; j < 8; ++j) xv[j] = *(const h2*)(xlb + off[j]);
#pragma unroll
            for (int j = 0; j < 8; ++j) {
                h2 t = xv[j] + xrv;
                h2 lk = __builtin_elementwise_max(t, t * slope);
                float sp = fmaf((float)lk.x, a0, (float)lk.y * a1);
                float w = exp2f(fminf(red8(sp) - sself, 110.f));
                lsum += w;
                acc0 = fmaf(w, (float)xv[j].x, acc0);
                acc1 = fmaf(w, (float)xv[j].y, acc1);
            }
        }
        for (; idx + 8 <= end; idx += 8) {   // 4 pairs
            int off[4];
            h2 xv[4];
#pragma unroll
            for (int j = 0; j < 4; ++j) off[j] = csr[idx + 2 * j + hh];
#pragma unroll
            for (int j = 0; j < 4; ++j) xv[j] = *(const h2*)(xlb + off[j]);
#pragma unroll
            for (int j = 0; j < 4; ++j) {
                h2 t = xv[j] + xrv;
                h2 lk = __builtin_elementwise_max(t, t * slope);
                float sp = fmaf((float)lk.x, a0, (float)lk.y * a1);
                float w = exp2f(fminf(red8(sp) - sself, 110.f));
                lsum += w;
                acc0 = fmaf(w, (float)xv[j].x, acc0);
                acc1 = fmaf(w, (float)xv[j].y, acc1);
            }
        }
        for (; idx < end; idx += 2) {         // masked pairs
            int e = idx + hh;
            bool valid = e < end;
            int off = csr[valid ? e : end - 1];
            h2 xv = *(const h2*)(xlb + off);
            h2 t = xv + xrv;
            h2 lk = __builtin_elementwise_max(t, t * slope);
            float sp = fmaf((float)lk.x, a0, (float)lk.y * a1);
            float w = exp2f(fminf(red8(sp) - sself, 110.f));
            w = valid ? w : 0.f;
            lsum += w;
            acc0 = fmaf(w, (float)xv.x, acc0);
            acc1 = fmaf(w, (float)xv.y, acc1);
        }
        // combine edge slots A/B (same channels, disjoint edges)
        lsum += __shfl_xor(lsum, 32);
        acc0 += __shfl_xor(acc0, 32);
        acc1 += __shfl_xor(acc1, 32);
        if (hh == 0) {
            float invl = 1.0f / lsum;
            float o0 = acc0 * invl + cb0;
            float o1 = acc1 * invl + cb1;
            float2 o = {o0, o1};
            *(float2*)(gbuf + (size_t)node * 64 + 2 * cl) = o;
            bs0 += o0; bs1 += o1;
            bq0 += o0 * o0; bq1 += o1 * o1;
        }
    }
    // block-reduce BN stats (channels 2cl, 2cl+1 live in lanes 0-31 of each wave)
    __shared__ float2 sred[1024];
    float2 z = {0.f, 0.f};
    float2 v1 = {bs0, bs1};
    sred[threadIdx.x] = (hh == 0) ? v1 : z;
    __syncthreads();
    if (threadIdx.x < 32) {
        float t0 = 0.f, t1 = 0.f;
#pragma unroll
        for (int w = 0; w < 16; ++w) { float2 s = sred[w * 64 + threadIdx.x]; t0 += s.x; t1 += s.y; }
        atomicAdd(&st[2 * threadIdx.x], t0);
        atomicAdd(&st[2 * threadIdx.x + 1], t1);
    }
    __syncthreads();
    float2 v2 = {bq0, bq1};
    sred[threadIdx.x] = (hh == 0) ? v2 : z;
    __syncthreads();
    if (threadIdx.x < 32) {
        float t0 = 0.f, t1 = 0.f;
#pragma unroll
        for (int w = 0; w < 16; ++w) { float2 s = sred[w * 64 + threadIdx.x]; t0 += s.x; t1 += s.y; }
        atomicAdd(&st[64 + 2 * threadIdx.x], t0);
        atomicAdd(&st[64 + 2 * threadIdx.x + 1], t1);
    }
}

// ---------------- pool, fused with layer-7 BN+ELU+residual ----------------

__global__ __launch_bounds__(256) void k_pool(GP ga, GP gbp, int nPer,
        const float* __restrict__ gamma, const float* __restrict__ beta, int n) {
    int bid = blockIdx.x;
    GP g = ga;
    if (bid >= nPer) { g = gbp; bid -= nPer; }
    int lane = threadIdx.x & 63, w = threadIdx.x >> 6;
    const float* st = g.stats + 7 * 128;
    float invn = 1.f / (float)n;
    float mu = st[lane] * invn;
    float var = st[64 + lane] * invn - mu * mu;
    float inv = rsqrtf(fmaxf(var, 0.f) + EPS);
    float gam = gamma[lane], bet = beta[lane];
    int chunk = (n + nPer - 1) / nPer;
    int s = bid * chunk;
    int e = min(s + chunk, n);
    float acc = 0.f;
    int cur = -1;
    for (int node = s + w; node < e; node += 4) {
        int bg = g.batch[node];  // wave-uniform
        size_t off = (size_t)node * 64 + lane;
        float gv = g.gb[off];
        float hv = g.h[off];
        float v = (gv - mu) * inv * gam + bet;
        float hn = hv + (v > 0.f ? v : expm1f(v));
        if (bg != cur) {
            if (cur >= 0) atomicAdd(&g.osum[cur * 64 + lane], acc);
            acc = 0.f; cur = bg;
        }
        acc += hn;
    }
    if (cur >= 0) atomicAdd(&g.osum[cur * 64 + lane], acc);
}

// ---------------- FC head (divides pooled sums by counts) ----------------

__device__ __forceinline__ int lb(const int* __restrict__ b, int n, int v) {
    int lo = 0, hi = n;
    while (lo < hi) { int mid = (lo + hi) >> 1; if (b[mid] < v) lo = mid + 1; else hi = mid; }
    return lo;
}

__global__ __launch_bounds__(256) void k_fc(const float* __restrict__ o1, const float* __restrict__ o2,
                                            const int* __restrict__ b1, const int* __restrict__ b2,
                                            const float* __restrict__ f1w, const float* __restrict__ f1b,
                                            const float* __restrict__ f2w, const float* __restrict__ f2b,
                                            const float* __restrict__ f3w, const float* __restrict__ f3b,
                                            float* __restrict__ out, int n) {
    int gid = blockIdx.x, t = threadIdx.x;
    __shared__ float cin[128];
    __shared__ float h1[256];
    __shared__ float red[128];
    __shared__ int cnts[2];
    if (t == 0) cnts[0] = lb(b1, n, gid + 1) - lb(b1, n, gid);
    if (t == 1) cnts[1] = lb(b2, n, gid + 1) - lb(b2, n, gid);
    __syncthreads();
    if (t < 64) {
        float c1 = (float)(cnts[0] > 0 ? cnts[0] : 1);
        float c2 = (float)(cnts[1] > 0 ? cnts[1] : 1);
        cin[t] = o1[gid * 64 + t] / c1;
        cin[64 + t] = o2[gid * 64 + t] / c2;
    }
    __syncthreads();
    float a = f1b[t];
#pragma unroll 8
    for (int k = 0; k < 128; ++k) a += cin[k] * f1w[k * 256 + t];
    h1[t] = fmaxf(a, 0.f);
    __syncthreads();
    if (t < 128) {
        float a2 = f2b[t];
#pragma unroll 8
        for (int k = 0; k < 256; ++k) a2 += h1[k] * f2w[k * 128 + t];
        red[t] = fmaxf(a2, 0.f) * f3w[t];
    }
    __syncthreads();
    for (int off = 64; off > 0; off >>= 1) {
        if (t < off) red[t] += red[t + off];
        __syncthreads();
    }
    if (t == 0) out[gid] = red[0] + f3b[0];
}

// ---------------- host ----------------

extern "C" void kernel_launch(void* const* d_in, const int* in_sizes, int n_in,
                              void* d_out, int out_size, void* d_ws, size_t ws_size,
                              hipStream_t stream) {
    const float* x1 = (const float*)d_in[0];
    const float* x2 = (const float*)d_in[1];
    const int* ei1 = (const int*)d_in[2];
    const int* ei2 = (const int*)d_in[3];
    const int* b1 = (const int*)d_in[4];
    const int* b2 = (const int*)d_in[5];
    const float* Wn = (const float*)d_in[6];
    const float* bnode = (const float*)d_in[7];
    const float* Wl = (const float*)d_in[8];
    const float* bl = (const float*)d_in[9];
    const float* Wr = (const float*)d_in[10];
    const float* br = (const float*)d_in[11];
    const float* att = (const float*)d_in[12];
    const float* cbias = (const float*)d_in[13];
    const float* gamma = (const float*)d_in[14];
    const float* beta = (const float*)d_in[15];
    const float* f1w = (const float*)d_in[16];
    const float* f1b = (const float*)d_in[17];
    const float* f2w = (const float*)d_in[18];
    const float* f2b = (const float*)d_in[19];
    const float* f3w = (const float*)d_in[20];
    const float* f3b = (const float*)d_in[21];
    float* out = (float*)d_out;

    const int N = N_NODES;
    const int EA = in_sizes[2] / 2;
    const int EB = in_sizes[3] / 2;
    const size_t INT_PG = 20096 + 20096 + 340096;  // deg, cursor, csr
    const size_t BIG = (size_t)N * 64;             // float-sized slot
    const size_t SMALL = 2 * 1024 + 2 * 2048;      // stats + osum
    const size_t WPK = 32768;                      // packed fp16 weights (uint32)
    const size_t dualBytes = 2 * INT_PG * 4 + (8 * BIG + SMALL + WPK) * 4;
    const int dual = (ws_size >= dualBytes) ? 1 : 0;

    int* ibase = (int*)d_ws;
    int* iA = ibase;
    int* iB = dual ? ibase + INT_PG : ibase;
    float* fbase = (float*)(ibase + (size_t)(dual ? 2 : 1) * INT_PG);
    float* hA = fbase;
    float* xlA = hA + BIG;      // fp16 xl (half of slot)
    float* xrA = xlA + BIG;     // fp16 xr (half of slot)
    float* gbA = xrA + BIG;
    float* hB = dual ? gbA + BIG : hA;
    float* xlB = dual ? hB + BIG : xlA;
    float* xrB = dual ? xlB + BIG : xrA;
    float* gbB = dual ? xrB + BIG : gbA;
    float* small = dual ? gbB + BIG : gbA + BIG;
    float* statsA = small;
    float* statsB = small + 1024;
    float* osumA = small + 2048;
    float* osumB = small + 4096;
    uint32_t* wpk = (uint32_t*)(small + SMALL);

    GP A, B;
    A.ei = ei1; A.batch = b1; A.x = x1;
    A.deg = iA; A.cursor = iA + 20096; A.csr = iA + 40192;
    A.h = hA; A.xlh = (__half*)xlA; A.xrh = (__half*)xrA;
    A.gb = gbA; A.stats = statsA; A.osum = osumA;
    B.ei = ei2; B.batch = b2; B.x = x2;
    B.deg = iB; B.cursor = iB + 20096; B.csr = iB + 40192;
    B.h = hB; B.xlh = (__half*)xlB; B.xrh = (__half*)xrB;
    B.gb = gbB; B.stats = statsB; B.osum = osumB;

    hipMemsetAsync(small, 0, SMALL * sizeof(float), stream);

    const int LIN2_NB = 625;   // per graph: one exact 32-node tile per block
    const int ATT_NB = 256;    // per graph, 1024-thread blocks, parity split
    const int POOL_NB = 250;   // per graph

    if (dual) {
        int Emax = EA > EB ? EA : EB;
        k_csr_init<<<(N + 255) / 256, 256, 0, stream>>>(A, B, N, 1);
        k_count<<<(Emax + 255) / 256, 256, 0, stream>>>(A, B, EA, EB, 1);
        k_scan<<<2, 1024, 0, stream>>>(A, B, N, EA + N, EB + N);
        k_scatter<<<(Emax + N + 255) / 256, 256, 0, stream>>>(A, B, EA, EB, N, 1);
        k_wcvt<<<64, 256, 0, stream>>>(Wl, Wr, wpk);
        for (int l = 0; l < 8; ++l) {
            const float* gm = l ? gamma + (l - 1) * 64 : gamma;
            const float* bt = l ? beta + (l - 1) * 64 : beta;
            k_lin2<<<2 * LIN2_NB, 256, 0, stream>>>(A, B, LIN2_NB, N,
                                                    wpk + l * 4096, bl + l * 64,
                                                    wpk + l * 4096 + 2048, br + l * 64, gm, bt,
                                                    Wn, bnode, l);
            k_attn<<<2 * ATT_NB, 1024, 0, stream>>>(A, B, ATT_NB, att + l * 64, cbias + l * 64, l, N);
        }
        k_pool<<<2 * POOL_NB, 256, 0, stream>>>(A, B, POOL_NB, gamma + 7 * 64, beta + 7 * 64, N);
    } else {
        for (int gi = 0; gi < 2; ++gi) {
            GP G = gi ? B : A;
            int E = gi ? EB : EA;
            k_csr_init<<<(N + 255) / 256, 256, 0, stream>>>(G, G, N, 0);
            k_count<<<(E + 255) / 256, 256, 0, stream>>>(G, G, E, E, 0);
            k_scan<<<1, 1024, 0, stream>>>(G, G, N, E + N, E + N);
            k_scatter<<<(E + N + 255) / 256, 256, 0, stream>>>(G, G, E, E, N, 0);
            if (gi == 0) k_wcvt<<<64, 256, 0, stream>>>(Wl, Wr, wpk);
            for (int l = 0; l < 8; ++l) {
                const float* gm = l ? gamma + (l - 1) * 64 : gamma;
                const float* bt = l ? beta + (l - 1) * 64 : beta;
                k_lin2<<<LIN2_NB, 256, 0, stream>>>(G, G, LIN2_NB, N,
                                                    wpk + l * 4096, bl + l * 64,
                                                    wpk + l * 4096 + 2048, br + l * 64, gm, bt,
                                                    Wn, bnode, l);
                k_attn<<<2 * ATT_NB, 1024, 0, stream>>>(G, G, ATT_NB, att + l * 64, cbias + l * 64, l, N);
            }
            k_pool<<<POOL_NB, 256, 0, stream>>>(G, G, POOL_NB, gamma + 7 * 64, beta + 7 * 64, N);
        }
    }
    k_fc<<<32, 256, 0, stream>>>(osumA, osumB, b1, b2, f1w, f1b, f2w, f2b, f3w, f3b, out, N);
}